// Round 2
// 626.291 us; speedup vs baseline: 1.1049x; 1.1049x over previous
//
#include <hip/hip_runtime.h>
#include <hip/hip_bf16.h>

#define T_ 1024
#define H_ 1024
#define I_ 512
#define E_ 64
#define S_ 2
#define NJOB 66              // 64 routed + 2 shared "jobs"
#define KSEL 8
#define GRP 8
#define GSIZE 8
#define TKG 4
#define ROWS_TOTAL (T_*KSEL + S_*T_)   // 10240

typedef __attribute__((ext_vector_type(8))) __bf16 bf16x8;
typedef __attribute__((ext_vector_type(8))) unsigned short u16x8;
typedef __attribute__((ext_vector_type(4))) unsigned short u16x4;
typedef __attribute__((ext_vector_type(4))) float f32x4;

__device__ inline unsigned short f2bf(float f) {
    unsigned u = __float_as_uint(f);
    u += 0x7FFFu + ((u >> 16) & 1u);   // round-to-nearest-even
    return (unsigned short)(u >> 16);
}

// pack two fp32 -> one u32 of two bf16 (RNE); compiler lowers to v_cvt_pk_bf16_f32
__device__ inline unsigned pk2bf(float a, float b) {
    unsigned short ua = __builtin_bit_cast(unsigned short, (__bf16)a);
    unsigned short ub = __builtin_bit_cast(unsigned short, (__bf16)b);
    return (unsigned)ua | ((unsigned)ub << 16);
}

// async global->LDS, 16B per lane. LDS dest must be wave_base + lane*16.
__device__ inline void async16(const void* g, void* l) {
    __builtin_amdgcn_global_load_lds(
        (const __attribute__((address_space(1))) unsigned int*)g,
        (__attribute__((address_space(3))) unsigned int*)(uintptr_t)l,
        16, 0, 0);
}

// ---------------- x -> bf16 ----------------
__global__ __launch_bounds__(256) void cvt_x_kernel(const float* __restrict__ x,
                                                    unsigned short* __restrict__ xb) {
    int i = (blockIdx.x * 256 + threadIdx.x) * 4;
    f32x4 v = *(const f32x4*)(x + i);
    u16x4 o;
    o[0] = f2bf(v[0]); o[1] = f2bf(v[1]); o[2] = f2bf(v[2]); o[3] = f2bf(v[3]);
    *(u16x4*)(xb + i) = o;
}

// ---------------- gating: LDS-tiled fp32 logits + grouped top-k ----------------
__global__ __launch_bounds__(256) void gate_kernel(const float* __restrict__ x,
                                                   const float* __restrict__ gate_w,
                                                   int* __restrict__ counts,
                                                   int* __restrict__ topk_idx,
                                                   float* __restrict__ topk_w) {
    __shared__ float Wt[64 * 65];
    __shared__ float Xs[4 * 65];
    __shared__ float lg[4 * 65];

    int tid = threadIdx.x;
    int t0 = blockIdx.x * 4;
    int e = tid & 63;
    int wq = tid >> 6;
    int er = tid >> 2;
    int kq = (tid & 3) * 16;
    int xk = tid & 63;

    float acc = 0.f;
    for (int kc = 0; kc < 16; ++kc) {
        const float* wp = gate_w + er * H_ + kc * 64 + kq;
        f32x4 w0 = *(const f32x4*)(wp);
        f32x4 w1 = *(const f32x4*)(wp + 4);
        f32x4 w2 = *(const f32x4*)(wp + 8);
        f32x4 w3 = *(const f32x4*)(wp + 12);
        float xv = x[(size_t)(t0 + wq) * H_ + kc * 64 + xk];
        __syncthreads();
#pragma unroll
        for (int i = 0; i < 4; ++i) {
            Wt[(kq + i) * 65 + er] = w0[i];
            Wt[(kq + 4 + i) * 65 + er] = w1[i];
            Wt[(kq + 8 + i) * 65 + er] = w2[i];
            Wt[(kq + 12 + i) * 65 + er] = w3[i];
        }
        Xs[wq * 65 + xk] = xv;
        __syncthreads();
#pragma unroll 8
        for (int k = 0; k < 64; ++k)
            acc += Wt[k * 65 + e] * Xs[wq * 65 + k];
    }
    lg[wq * 65 + e] = acc;
    __syncthreads();

    if (tid < 4) {
        int t = t0 + tid;
        const float* L = &lg[tid * 65];
        float cv[GRP * TKG];
        int   ce[GRP * TKG];
        for (int g = 0; g < GRP; ++g) {
            unsigned used = 0;
            for (int r = 0; r < TKG; ++r) {
                float best = -INFINITY; int bi = 0;
                for (int j = 0; j < GSIZE; ++j) {
                    if (used & (1u << j)) continue;
                    float v = L[g * GSIZE + j];
                    if (v > best) { best = v; bi = j; }
                }
                used |= 1u << bi;
                cv[g * TKG + r] = best;
                ce[g * TKG + r] = g * GSIZE + bi;
            }
        }
        float sv[KSEL]; int si[KSEL];
        unsigned used = 0;
        float sum = 0.0f;
        for (int r = 0; r < KSEL; ++r) {
            float best = -INFINITY; int bi = 0;
            for (int j = 0; j < GRP * TKG; ++j) {
                if (used & (1u << j)) continue;
                if (cv[j] > best) { best = cv[j]; bi = j; }
            }
            used |= 1u << bi;
            sv[r] = best; si[r] = ce[bi];
            sum += best;
        }
        float inv = 1.0f / (sum + 1e-20f);
        for (int r = 0; r < KSEL; ++r) {
            topk_idx[t * KSEL + r] = si[r];
            topk_w[t * KSEL + r] = sv[r] * inv;
            atomicAdd(&counts[si[r]], 1);
        }
    }
}

// ---------------- prefix sum over 66 job counts ----------------
__global__ void prefix_kernel(int* __restrict__ counts, int* __restrict__ offsets,
                              int* __restrict__ cursor) {
    if (threadIdx.x == 0) {
        counts[E_] = T_;
        counts[E_ + 1] = T_;
        int acc = 0;
        for (int j = 0; j < NJOB; ++j) {
            offsets[j] = acc;
            cursor[j] = acc;
            acc += counts[j];
        }
        offsets[NJOB] = acc;
    }
}

// ---------------- scatter (token, weight) into compact per-job segments ----------------
__global__ __launch_bounds__(256) void place_kernel(const int* __restrict__ topk_idx,
                                                    const float* __restrict__ topk_w,
                                                    const int* __restrict__ offsets,
                                                    int* __restrict__ cursor,
                                                    int* __restrict__ row_token,
                                                    float* __restrict__ row_w) {
    int p = blockIdx.x * 256 + threadIdx.x;
    if (p < T_ * KSEL) {
        int t = p >> 3;
        int e = topk_idx[p];
        int slot = atomicAdd(&cursor[e], 1);
        row_token[slot] = t;
        row_w[slot] = topk_w[p];
    } else if (p < T_ * KSEL + S_ * T_) {
        int q = p - T_ * KSEL;
        int s = q >> 10;
        int t = q & (T_ - 1);
        int slot = offsets[E_ + s] + t;
        row_token[slot] = t;
        row_w[slot] = 1.0f;
    }
}

// ---------------- GEMM1: hidden = silu(x@Wg)*(x@Wu) ----------------
// A: gathered xb rows [128 x 64k] bf16 via global_load_lds (XOR-swizzled chunks).
// B: fp32 weights [k][n] read DIRECTLY (no pre-transpose pass): each thread loads a
//    4k x 4n fp32 sub-tile coalesced, transposes+converts in registers, and writes
//    b64 chunks into the SAME XOR-swizzled [n][k] bf16 LDS layout the MFMA reads use.
//    Bank check: b64 write addr = n*128 + ((k>>3)^(n&7))*16 + (k&4)*2 -> the
//    (swizzle, k-half) bits span all 32 banks, 4 accesses/bank = conflict-free min.
__global__ __launch_bounds__(256) void gateup_kernel(const unsigned short* __restrict__ xb,
                                                     const float* __restrict__ w_gu,
                                                     const float* __restrict__ s_gu,
                                                     const int* __restrict__ offsets,
                                                     const int* __restrict__ row_token,
                                                     unsigned short* __restrict__ hidden) {
    int job = blockIdx.x, mt = blockIdx.y, nt = blockIdx.z;
    int seg = offsets[job];
    int cnt = offsets[job + 1] - seg;
    int m0 = mt * 128;
    if (m0 >= cnt) return;
    const float* W = (job < E_) ? (w_gu + (size_t)job * H_ * (2 * I_))
                                : (s_gu + (size_t)(job - E_) * H_ * (2 * I_));
    int n0 = nt * 64;

    __shared__ unsigned short As[128 * 64];   // 16 KB
    __shared__ unsigned short Bg[64 * 64];    // 8 KB
    __shared__ unsigned short Bu[64 * 64];    // 8 KB

    int tid = threadIdx.x;
    int wv = tid >> 6, lane = tid & 63, lrow = lane & 15, lq = lane >> 4;

    const unsigned short* asrc[4];
#pragma unroll
    for (int i = 0; i < 4; ++i) {
        int d = i * 256 + tid;            // chunk 0..1023
        int row = d >> 3;
        int kc = (d & 7) ^ (row & 7);
        int r = m0 + row;
        int gi = seg + (r < cnt ? r : 0);
        asrc[i] = xb + (size_t)row_token[gi] * H_ + kc * 8;
    }

    // B staging geometry: thread owns k rows bk..bk+3, cols bn..bn+3 of the 64x64 tile
    int bk = (tid & 15) * 4;
    int bn = (tid >> 4) * 4;
    int c0 = bk >> 3;                 // k-chunk (8 bf16)
    int h8 = (bk & 4) * 2;            // byte offset within chunk: 0 or 8
    const float* bbase = W + (size_t)bk * (2 * I_) + n0 + bn;

    f32x4 accg[2][4], accu[2][4];
    f32x4 zero = {0.f, 0.f, 0.f, 0.f};
#pragma unroll
    for (int a = 0; a < 2; ++a)
#pragma unroll
        for (int c = 0; c < 4; ++c) { accg[a][c] = zero; accu[a][c] = zero; }

    // prefetch B regs for kt=0
    f32x4 g[4], u[4];
#pragma unroll
    for (int r = 0; r < 4; ++r) {
        g[r] = *(const f32x4*)(bbase + (size_t)r * (2 * I_));
        u[r] = *(const f32x4*)(bbase + (size_t)r * (2 * I_) + I_);
    }

    for (int kt = 0; kt < H_ / 64; ++kt) {
        int ko = kt * 64;
#pragma unroll
        for (int i = 0; i < 4; ++i)
            async16(asrc[i] + ko, &As[(i * 256 + tid) * 8]);

        // transpose+convert held B regs -> LDS (chunk-swizzled [n][k] bf16)
#pragma unroll
        for (int j = 0; j < 4; ++j) {
            int nj = bn + j;
            int byteoff = nj * 128 + ((c0 ^ (nj & 7)) * 16) + h8;
            uint2 vg, vu;
            vg.x = pk2bf(g[0][j], g[1][j]); vg.y = pk2bf(g[2][j], g[3][j]);
            vu.x = pk2bf(u[0][j], u[1][j]); vu.y = pk2bf(u[2][j], u[3][j]);
            *(uint2*)((char*)Bg + byteoff) = vg;
            *(uint2*)((char*)Bu + byteoff) = vu;
        }

        // issue B loads for next k-step (latency folds into the barrier drain)
        {
            int kn = ((kt + 1) & 15) * 64;
            const float* bp = bbase + (size_t)kn * (2 * I_);
#pragma unroll
            for (int r = 0; r < 4; ++r) {
                g[r] = *(const f32x4*)(bp + (size_t)r * (2 * I_));
                u[r] = *(const f32x4*)(bp + (size_t)r * (2 * I_) + I_);
            }
        }
        __syncthreads();

#pragma unroll
        for (int kk = 0; kk < 2; ++kk) {
            bf16x8 a[2];
#pragma unroll
            for (int rb = 0; rb < 2; ++rb) {
                int R = wv * 32 + rb * 16 + lrow;
                a[rb] = *(const bf16x8*)&As[R * 64 + (((lq + kk * 4) ^ (R & 7)) * 8)];
            }
#pragma unroll
            for (int cb = 0; cb < 4; ++cb) {
                int n = cb * 16 + lrow;
                int koff = ((lq + kk * 4) ^ (n & 7)) * 8;
                bf16x8 bg = *(const bf16x8*)&Bg[n * 64 + koff];
                bf16x8 bu = *(const bf16x8*)&Bu[n * 64 + koff];
#pragma unroll
                for (int rb = 0; rb < 2; ++rb) {
                    accg[rb][cb] = __builtin_amdgcn_mfma_f32_16x16x32_bf16(a[rb], bg, accg[rb][cb], 0, 0, 0);
                    accu[rb][cb] = __builtin_amdgcn_mfma_f32_16x16x32_bf16(a[rb], bu, accu[rb][cb], 0, 0, 0);
                }
            }
        }
        __syncthreads();
    }

#pragma unroll
    for (int rb = 0; rb < 2; ++rb)
#pragma unroll
        for (int cb = 0; cb < 4; ++cb)
#pragma unroll
            for (int r = 0; r < 4; ++r) {
                int row = wv * 32 + rb * 16 + lq * 4 + r;
                if (m0 + row < cnt) {
                    float gg = accg[rb][cb][r];
                    float uu = accu[rb][cb][r];
                    float hh = gg / (1.0f + __expf(-gg)) * uu;
                    hidden[(size_t)(seg + m0 + row) * I_ + n0 + cb * 16 + lrow] = f2bf(hh);
                }
            }
}

// ---------------- GEMM2: out += w * (hidden @ Wd); B fp32 direct, same staging ----------------
__global__ __launch_bounds__(256) void down_kernel(const unsigned short* __restrict__ hidden,
                                                   const float* __restrict__ w_d,
                                                   const float* __restrict__ s_d,
                                                   const int* __restrict__ offsets,
                                                   const int* __restrict__ row_token,
                                                   const float* __restrict__ row_w,
                                                   float* __restrict__ out) {
    int job = blockIdx.x, mt = blockIdx.y, nt = blockIdx.z;
    int seg = offsets[job];
    int cnt = offsets[job + 1] - seg;
    int m0 = mt * 128;
    if (m0 >= cnt) return;
    const float* W = (job < E_) ? (w_d + (size_t)job * I_ * H_)
                                : (s_d + (size_t)(job - E_) * I_ * H_);
    int n0 = nt * 64;

    __shared__ unsigned short As[128 * 64];   // 16 KB
    __shared__ unsigned short Bs[64 * 64];    // 8 KB

    int tid = threadIdx.x;
    int wv = tid >> 6, lane = tid & 63, lrow = lane & 15, lq = lane >> 4;

    const unsigned short* asrc[4];
#pragma unroll
    for (int i = 0; i < 4; ++i) {
        int d = i * 256 + tid;
        int row = d >> 3;
        int kc = (d & 7) ^ (row & 7);
        int r = m0 + row;
        int gi = seg + (r < cnt ? r : 0);
        asrc[i] = hidden + (size_t)gi * I_ + kc * 8;
    }

    int bk = (tid & 15) * 4;
    int bn = (tid >> 4) * 4;
    int c0 = bk >> 3;
    int h8 = (bk & 4) * 2;
    const float* bbase = W + (size_t)bk * H_ + n0 + bn;

    f32x4 acc[2][4];
    f32x4 zero = {0.f, 0.f, 0.f, 0.f};
#pragma unroll
    for (int a = 0; a < 2; ++a)
#pragma unroll
        for (int c = 0; c < 4; ++c) acc[a][c] = zero;

    f32x4 d4[4];
#pragma unroll
    for (int r = 0; r < 4; ++r)
        d4[r] = *(const f32x4*)(bbase + (size_t)r * H_);

    for (int kt = 0; kt < I_ / 64; ++kt) {
        int ko = kt * 64;
#pragma unroll
        for (int i = 0; i < 4; ++i)
            async16(asrc[i] + ko, &As[(i * 256 + tid) * 8]);

#pragma unroll
        for (int j = 0; j < 4; ++j) {
            int nj = bn + j;
            int byteoff = nj * 128 + ((c0 ^ (nj & 7)) * 16) + h8;
            uint2 vb;
            vb.x = pk2bf(d4[0][j], d4[1][j]); vb.y = pk2bf(d4[2][j], d4[3][j]);
            *(uint2*)((char*)Bs + byteoff) = vb;
        }
        {
            int kn = ((kt + 1) & 7) * 64;
            const float* bp = bbase + (size_t)kn * H_;
#pragma unroll
            for (int r = 0; r < 4; ++r)
                d4[r] = *(const f32x4*)(bp + (size_t)r * H_);
        }
        __syncthreads();

#pragma unroll
        for (int kk = 0; kk < 2; ++kk) {
            bf16x8 a[2];
#pragma unroll
            for (int rb = 0; rb < 2; ++rb) {
                int R = wv * 32 + rb * 16 + lrow;
                a[rb] = *(const bf16x8*)&As[R * 64 + (((lq + kk * 4) ^ (R & 7)) * 8)];
            }
#pragma unroll
            for (int cb = 0; cb < 4; ++cb) {
                int n = cb * 16 + lrow;
                bf16x8 b = *(const bf16x8*)&Bs[n * 64 + (((lq + kk * 4) ^ (n & 7)) * 8)];
#pragma unroll
                for (int rb = 0; rb < 2; ++rb)
                    acc[rb][cb] = __builtin_amdgcn_mfma_f32_16x16x32_bf16(a[rb], b, acc[rb][cb], 0, 0, 0);
            }
        }
        __syncthreads();
    }

#pragma unroll
    for (int rb = 0; rb < 2; ++rb)
#pragma unroll
        for (int r = 0; r < 4; ++r) {
            int row = wv * 32 + rb * 16 + lq * 4 + r;
            if (m0 + row < cnt) {
                int gi = seg + m0 + row;
                int tok = row_token[gi];
                float w = row_w[gi];
#pragma unroll
                for (int cb = 0; cb < 4; ++cb)
                    atomicAdd(&out[(size_t)tok * H_ + n0 + cb * 16 + lrow],
                              acc[rb][cb][r] * w);
            }
        }
}

extern "C" void kernel_launch(void* const* d_in, const int* in_sizes, int n_in,
                              void* d_out, int out_size, void* d_ws, size_t ws_size,
                              hipStream_t stream) {
    const float* x      = (const float*)d_in[0];
    const float* gate_w = (const float*)d_in[1];
    const float* w_gu   = (const float*)d_in[2];
    const float* w_d    = (const float*)d_in[3];
    const float* s_gu   = (const float*)d_in[4];
    const float* s_d    = (const float*)d_in[5];
    float* out = (float*)d_out;

    char* ws = (char*)d_ws;
    size_t off = 0;
    auto carve = [&](size_t bytes) -> void* {
        void* p = ws + off;
        off += (bytes + 255) & ~(size_t)255;
        return p;
    };
    int* counts            = (int*)carve(NJOB * 4);
    int* offsets           = (int*)carve((NJOB + 1) * 4);
    int* cursor            = (int*)carve(NJOB * 4);
    int* topk_idx          = (int*)carve(T_ * KSEL * 4);
    float* topk_w          = (float*)carve(T_ * KSEL * 4);
    int* row_token         = (int*)carve(ROWS_TOTAL * 4);
    float* row_w           = (float*)carve(ROWS_TOTAL * 4);
    unsigned short* xb     = (unsigned short*)carve((size_t)T_ * H_ * 2);
    unsigned short* hidden = (unsigned short*)carve((size_t)ROWS_TOTAL * I_ * 2);

    hipMemsetAsync(out, 0, (size_t)T_ * H_ * 4, stream);
    hipMemsetAsync(counts, 0, NJOB * 4, stream);

    cvt_x_kernel<<<(T_ * H_ / 4) / 256, 256, 0, stream>>>(x, xb);
    gate_kernel<<<T_ / 4, 256, 0, stream>>>(x, gate_w, counts, topk_idx, topk_w);
    prefix_kernel<<<1, 64, 0, stream>>>(counts, offsets, cursor);
    place_kernel<<<(ROWS_TOTAL + 255) / 256, 256, 0, stream>>>(topk_idx, topk_w, offsets,
                                                               cursor, row_token, row_w);
    gateup_kernel<<<dim3(NJOB, T_ / 128, I_ / 64), 256, 0, stream>>>(xb, w_gu, s_gu, offsets,
                                                                     row_token, hidden);
    down_kernel<<<dim3(NJOB, T_ / 128, H_ / 64), 256, 0, stream>>>(hidden, w_d, s_d, offsets,
                                                                   row_token, row_w, out);
}

// Round 3
// 621.713 us; speedup vs baseline: 1.1131x; 1.0074x over previous
//
#include <hip/hip_runtime.h>
#include <hip/hip_bf16.h>

#define T_ 1024
#define H_ 1024
#define I_ 512
#define E_ 64
#define S_ 2
#define NJOB 66              // 64 routed + 2 shared "jobs"
#define KSEL 8
#define GRP 8
#define GSIZE 8
#define TKG 4
#define ROWS_TOTAL (T_*KSEL + S_*T_)   // 10240
#define SH0 (T_*KSEL)                  // shared expert 0 slot base = 8192
#define SH1 (T_*KSEL + T_)             // shared expert 1 slot base = 9216

typedef __attribute__((ext_vector_type(8))) __bf16 bf16x8;
typedef __attribute__((ext_vector_type(8))) unsigned short u16x8;
typedef __attribute__((ext_vector_type(4))) unsigned short u16x4;
typedef __attribute__((ext_vector_type(4))) float f32x4;

__device__ inline unsigned short f2bf(float f) {
    unsigned u = __float_as_uint(f);
    u += 0x7FFFu + ((u >> 16) & 1u);   // round-to-nearest-even
    return (unsigned short)(u >> 16);
}

// pack two fp32 -> one u32 of two bf16 (RNE)
__device__ inline unsigned pk2bf(float a, float b) {
    unsigned short ua = __builtin_bit_cast(unsigned short, (__bf16)a);
    unsigned short ub = __builtin_bit_cast(unsigned short, (__bf16)b);
    return (unsigned)ua | ((unsigned)ub << 16);
}

// async global->LDS, 16B per lane. LDS dest must be wave_base + lane*16.
__device__ inline void async16(const void* g, void* l) {
    __builtin_amdgcn_global_load_lds(
        (const __attribute__((address_space(1))) unsigned int*)g,
        (__attribute__((address_space(3))) unsigned int*)(uintptr_t)l,
        16, 0, 0);
}

// ---------------- x -> bf16 ----------------
__global__ __launch_bounds__(256) void cvt_x_kernel(const float* __restrict__ x,
                                                    unsigned short* __restrict__ xb) {
    int i = (blockIdx.x * 256 + threadIdx.x) * 4;
    f32x4 v = *(const f32x4*)(x + i);
    u16x4 o;
    o[0] = f2bf(v[0]); o[1] = f2bf(v[1]); o[2] = f2bf(v[2]); o[3] = f2bf(v[3]);
    *(u16x4*)(xb + i) = o;
}

// ---------------- gating: LDS-tiled fp32 logits + grouped top-k ----------------
__global__ __launch_bounds__(256) void gate_kernel(const float* __restrict__ x,
                                                   const float* __restrict__ gate_w,
                                                   int* __restrict__ counts,
                                                   int* __restrict__ topk_idx,
                                                   float* __restrict__ topk_w) {
    __shared__ float Wt[64 * 65];
    __shared__ float Xs[4 * 65];
    __shared__ float lg[4 * 65];

    int tid = threadIdx.x;
    int t0 = blockIdx.x * 4;
    int e = tid & 63;
    int wq = tid >> 6;
    int er = tid >> 2;
    int kq = (tid & 3) * 16;
    int xk = tid & 63;

    float acc = 0.f;
    for (int kc = 0; kc < 16; ++kc) {
        const float* wp = gate_w + er * H_ + kc * 64 + kq;
        f32x4 w0 = *(const f32x4*)(wp);
        f32x4 w1 = *(const f32x4*)(wp + 4);
        f32x4 w2 = *(const f32x4*)(wp + 8);
        f32x4 w3 = *(const f32x4*)(wp + 12);
        float xv = x[(size_t)(t0 + wq) * H_ + kc * 64 + xk];
        __syncthreads();
#pragma unroll
        for (int i = 0; i < 4; ++i) {
            Wt[(kq + i) * 65 + er] = w0[i];
            Wt[(kq + 4 + i) * 65 + er] = w1[i];
            Wt[(kq + 8 + i) * 65 + er] = w2[i];
            Wt[(kq + 12 + i) * 65 + er] = w3[i];
        }
        Xs[wq * 65 + xk] = xv;
        __syncthreads();
#pragma unroll 8
        for (int k = 0; k < 64; ++k)
            acc += Wt[k * 65 + e] * Xs[wq * 65 + k];
    }
    lg[wq * 65 + e] = acc;
    __syncthreads();

    if (tid < 4) {
        int t = t0 + tid;
        const float* L = &lg[tid * 65];
        float cv[GRP * TKG];
        int   ce[GRP * TKG];
        for (int g = 0; g < GRP; ++g) {
            unsigned used = 0;
            for (int r = 0; r < TKG; ++r) {
                float best = -INFINITY; int bi = 0;
                for (int j = 0; j < GSIZE; ++j) {
                    if (used & (1u << j)) continue;
                    float v = L[g * GSIZE + j];
                    if (v > best) { best = v; bi = j; }
                }
                used |= 1u << bi;
                cv[g * TKG + r] = best;
                ce[g * TKG + r] = g * GSIZE + bi;
            }
        }
        float sv[KSEL]; int si[KSEL];
        unsigned used = 0;
        float sum = 0.0f;
        for (int r = 0; r < KSEL; ++r) {
            float best = -INFINITY; int bi = 0;
            for (int j = 0; j < GRP * TKG; ++j) {
                if (used & (1u << j)) continue;
                if (cv[j] > best) { best = cv[j]; bi = j; }
            }
            used |= 1u << bi;
            sv[r] = best; si[r] = ce[bi];
            sum += best;
        }
        float inv = 1.0f / (sum + 1e-20f);
        for (int r = 0; r < KSEL; ++r) {
            topk_idx[t * KSEL + r] = si[r];
            topk_w[t * KSEL + r] = sv[r] * inv;
            atomicAdd(&counts[si[r]], 1);
        }
    }
}

// ---------------- prefix sum over 66 job counts (wave-parallel scan) ----------------
__global__ __launch_bounds__(128) void prefix_kernel(const int* __restrict__ counts,
                                                     int* __restrict__ offsets,
                                                     int* __restrict__ cursor) {
    __shared__ int c[NJOB];
    int tid = threadIdx.x;
    int own = 0;
    if (tid < NJOB) {
        own = (tid < E_) ? counts[tid] : T_;
        c[tid] = own;
    }
    __syncthreads();
    for (int d = 1; d < NJOB; d <<= 1) {
        int v = 0;
        if (tid < NJOB && tid >= d) v = c[tid - d];
        __syncthreads();
        if (tid < NJOB) c[tid] += v;
        __syncthreads();
    }
    if (tid < NJOB) {
        int excl = c[tid] - own;
        offsets[tid] = excl;
        cursor[tid] = excl;
    }
    if (tid == 0) offsets[NJOB] = ROWS_TOTAL;
}

// ---------------- scatter token ids into compact per-job segments; record slot map ----------------
__global__ __launch_bounds__(256) void place_kernel(const int* __restrict__ topk_idx,
                                                    const int* __restrict__ offsets,
                                                    int* __restrict__ cursor,
                                                    int* __restrict__ row_token,
                                                    int* __restrict__ slot_map) {
    int p = blockIdx.x * 256 + threadIdx.x;
    if (p < T_ * KSEL) {
        int t = p >> 3;
        int e = topk_idx[p];
        int slot = atomicAdd(&cursor[e], 1);
        row_token[slot] = t;
        slot_map[p] = slot;
    } else if (p < T_ * KSEL + S_ * T_) {
        int q = p - T_ * KSEL;
        int s = q >> 10;
        int t = q & (T_ - 1);
        int slot = offsets[E_ + s] + t;
        row_token[slot] = t;
    }
}

// ---------------- GEMM1: hidden = silu(x@Wg)*(x@Wu); MT=256, 512 threads ----------------
// A: gathered xb rows [256 x 64k] bf16 via global_load_lds (XOR-swizzled chunks).
// B: fp32 weights [k][n] read directly; per thread 2k x 4n sub-tile, reg transpose+cvt,
//    ds_write_b32 into the XOR-swizzled [n][k] bf16 layout (bank-verified: 2/bank = free).
__global__ __launch_bounds__(512) void gateup_kernel(const unsigned short* __restrict__ xb,
                                                     const float* __restrict__ w_gu,
                                                     const float* __restrict__ s_gu,
                                                     const int* __restrict__ offsets,
                                                     const int* __restrict__ row_token,
                                                     unsigned short* __restrict__ hidden) {
    int job = blockIdx.x, mt = blockIdx.y, nt = blockIdx.z;
    int seg = offsets[job];
    int cnt = offsets[job + 1] - seg;
    int m0 = mt * 256;
    if (m0 >= cnt) return;
    const float* W = (job < E_) ? (w_gu + (size_t)job * H_ * (2 * I_))
                                : (s_gu + (size_t)(job - E_) * H_ * (2 * I_));
    int n0 = nt * 64;

    __shared__ unsigned short As[256 * 64];   // 32 KB
    __shared__ unsigned short Bg[64 * 64];    // 8 KB
    __shared__ unsigned short Bu[64 * 64];    // 8 KB

    int tid = threadIdx.x;
    int wv = tid >> 6, lane = tid & 63, lrow = lane & 15, lq = lane >> 4;

    const unsigned short* asrc[4];
#pragma unroll
    for (int i = 0; i < 4; ++i) {
        int d = i * 512 + tid;            // chunk 0..2047
        int row = d >> 3;
        int kc = (d & 7) ^ (row & 7);
        int r = m0 + row;
        int gi = seg + (r < cnt ? r : 0);
        asrc[i] = xb + (size_t)row_token[gi] * H_ + kc * 8;
    }

    // B staging: thread owns k rows bk..bk+1, cols bn..bn+3 of the 64x64 tile
    int bk = (tid & 31) * 2;
    int bn = (tid >> 5) * 4;          // 0..60
    int c0 = bk >> 3;                 // k-chunk
    int hb = (bk & 7) * 2;            // byte offset within 16B chunk (0,4,8,12)
    const float* bbase = W + (size_t)bk * (2 * I_) + n0 + bn;

    f32x4 accg[2][4], accu[2][4];
    f32x4 zero = {0.f, 0.f, 0.f, 0.f};
#pragma unroll
    for (int a = 0; a < 2; ++a)
#pragma unroll
        for (int c = 0; c < 4; ++c) { accg[a][c] = zero; accu[a][c] = zero; }

    // prefetch B regs for kt=0
    f32x4 g[2], u[2];
#pragma unroll
    for (int r = 0; r < 2; ++r) {
        g[r] = *(const f32x4*)(bbase + (size_t)r * (2 * I_));
        u[r] = *(const f32x4*)(bbase + (size_t)r * (2 * I_) + I_);
    }

    for (int kt = 0; kt < H_ / 64; ++kt) {
        int ko = kt * 64;
#pragma unroll
        for (int i = 0; i < 4; ++i)
            async16(asrc[i] + ko, &As[(i * 512 + tid) * 8]);

        // transpose+convert held B regs -> LDS (chunk-swizzled [n][k] bf16)
#pragma unroll
        for (int j = 0; j < 4; ++j) {
            int nj = bn + j;
            int byteoff = nj * 128 + ((c0 ^ (nj & 7)) * 16) + hb;
            *(unsigned*)((char*)Bg + byteoff) = pk2bf(g[0][j], g[1][j]);
            *(unsigned*)((char*)Bu + byteoff) = pk2bf(u[0][j], u[1][j]);
        }

        // issue B loads for next k-step
        {
            int kn = ((kt + 1) & 15) * 64;
            const float* bp = bbase + (size_t)kn * (2 * I_);
#pragma unroll
            for (int r = 0; r < 2; ++r) {
                g[r] = *(const f32x4*)(bp + (size_t)r * (2 * I_));
                u[r] = *(const f32x4*)(bp + (size_t)r * (2 * I_) + I_);
            }
        }
        __syncthreads();

#pragma unroll
        for (int kk = 0; kk < 2; ++kk) {
            bf16x8 a[2];
#pragma unroll
            for (int rb = 0; rb < 2; ++rb) {
                int R = wv * 32 + rb * 16 + lrow;
                a[rb] = *(const bf16x8*)&As[R * 64 + (((lq + kk * 4) ^ (R & 7)) * 8)];
            }
#pragma unroll
            for (int cb = 0; cb < 4; ++cb) {
                int n = cb * 16 + lrow;
                int koff = ((lq + kk * 4) ^ (n & 7)) * 8;
                bf16x8 bg = *(const bf16x8*)&Bg[n * 64 + koff];
                bf16x8 bu = *(const bf16x8*)&Bu[n * 64 + koff];
#pragma unroll
                for (int rb = 0; rb < 2; ++rb) {
                    accg[rb][cb] = __builtin_amdgcn_mfma_f32_16x16x32_bf16(a[rb], bg, accg[rb][cb], 0, 0, 0);
                    accu[rb][cb] = __builtin_amdgcn_mfma_f32_16x16x32_bf16(a[rb], bu, accu[rb][cb], 0, 0, 0);
                }
            }
        }
        __syncthreads();
    }

#pragma unroll
    for (int rb = 0; rb < 2; ++rb)
#pragma unroll
        for (int cb = 0; cb < 4; ++cb)
#pragma unroll
            for (int r = 0; r < 4; ++r) {
                int row = wv * 32 + rb * 16 + lq * 4 + r;
                if (m0 + row < cnt) {
                    float gg = accg[rb][cb][r];
                    float uu = accu[rb][cb][r];
                    float hh = gg / (1.0f + __expf(-gg)) * uu;
                    hidden[(size_t)(seg + m0 + row) * I_ + n0 + cb * 16 + lrow] = f2bf(hh);
                }
            }
}

// ---------------- GEMM2: yrow = hidden @ Wd (unweighted, plain stores); MT=256 ----------------
__global__ __launch_bounds__(512) void down_kernel(const unsigned short* __restrict__ hidden,
                                                   const float* __restrict__ w_d,
                                                   const float* __restrict__ s_d,
                                                   const int* __restrict__ offsets,
                                                   float* __restrict__ yrow) {
    int job = blockIdx.x, mt = blockIdx.y, nt = blockIdx.z;
    int seg = offsets[job];
    int cnt = offsets[job + 1] - seg;
    int m0 = mt * 256;
    if (m0 >= cnt) return;
    const float* W = (job < E_) ? (w_d + (size_t)job * I_ * H_)
                                : (s_d + (size_t)(job - E_) * I_ * H_);
    int n0 = nt * 64;

    __shared__ unsigned short As[256 * 64];   // 32 KB
    __shared__ unsigned short Bs[64 * 64];    // 8 KB

    int tid = threadIdx.x;
    int wv = tid >> 6, lane = tid & 63, lrow = lane & 15, lq = lane >> 4;

    const unsigned short* asrc[4];
#pragma unroll
    for (int i = 0; i < 4; ++i) {
        int d = i * 512 + tid;
        int row = d >> 3;
        int kc = (d & 7) ^ (row & 7);
        int r = m0 + row;
        int gi = seg + (r < cnt ? r : 0);
        asrc[i] = hidden + (size_t)gi * I_ + kc * 8;
    }

    int bk = (tid & 31) * 2;
    int bn = (tid >> 5) * 4;
    int c0 = bk >> 3;
    int hb = (bk & 7) * 2;
    const float* bbase = W + (size_t)bk * H_ + n0 + bn;

    f32x4 acc[2][4];
    f32x4 zero = {0.f, 0.f, 0.f, 0.f};
#pragma unroll
    for (int a = 0; a < 2; ++a)
#pragma unroll
        for (int c = 0; c < 4; ++c) acc[a][c] = zero;

    f32x4 d4[2];
#pragma unroll
    for (int r = 0; r < 2; ++r)
        d4[r] = *(const f32x4*)(bbase + (size_t)r * H_);

    for (int kt = 0; kt < I_ / 64; ++kt) {
        int ko = kt * 64;
#pragma unroll
        for (int i = 0; i < 4; ++i)
            async16(asrc[i] + ko, &As[(i * 512 + tid) * 8]);

#pragma unroll
        for (int j = 0; j < 4; ++j) {
            int nj = bn + j;
            int byteoff = nj * 128 + ((c0 ^ (nj & 7)) * 16) + hb;
            *(unsigned*)((char*)Bs + byteoff) = pk2bf(d4[0][j], d4[1][j]);
        }
        {
            int kn = ((kt + 1) & 7) * 64;
            const float* bp = bbase + (size_t)kn * H_;
#pragma unroll
            for (int r = 0; r < 2; ++r)
                d4[r] = *(const f32x4*)(bp + (size_t)r * H_);
        }
        __syncthreads();

#pragma unroll
        for (int kk = 0; kk < 2; ++kk) {
            bf16x8 a[2];
#pragma unroll
            for (int rb = 0; rb < 2; ++rb) {
                int R = wv * 32 + rb * 16 + lrow;
                a[rb] = *(const bf16x8*)&As[R * 64 + (((lq + kk * 4) ^ (R & 7)) * 8)];
            }
#pragma unroll
            for (int cb = 0; cb < 4; ++cb) {
                int n = cb * 16 + lrow;
                bf16x8 b = *(const bf16x8*)&Bs[n * 64 + (((lq + kk * 4) ^ (n & 7)) * 8)];
#pragma unroll
                for (int rb = 0; rb < 2; ++rb)
                    acc[rb][cb] = __builtin_amdgcn_mfma_f32_16x16x32_bf16(a[rb], b, acc[rb][cb], 0, 0, 0);
            }
        }
        __syncthreads();
    }

#pragma unroll
    for (int rb = 0; rb < 2; ++rb)
#pragma unroll
        for (int r = 0; r < 4; ++r) {
            int row = wv * 32 + rb * 16 + lq * 4 + r;
            if (m0 + row < cnt) {
#pragma unroll
                for (int cb = 0; cb < 4; ++cb)
                    yrow[(size_t)(seg + m0 + row) * H_ + n0 + cb * 16 + lrow] = acc[rb][cb][r];
            }
        }
}

// ---------------- reduce: out[t] = sum_k w_k*yrow[slot_k] + yrow[sh0+t] + yrow[sh1+t] ----------------
__global__ __launch_bounds__(256) void reduce_kernel(const float* __restrict__ yrow,
                                                     const int* __restrict__ slot_map,
                                                     const float* __restrict__ topk_w,
                                                     float* __restrict__ out) {
    int t = blockIdx.x;
    __shared__ int sl[KSEL];
    __shared__ float sw[KSEL];
    if (threadIdx.x < KSEL) {
        sl[threadIdx.x] = slot_map[t * KSEL + threadIdx.x];
        sw[threadIdx.x] = topk_w[t * KSEL + threadIdx.x];
    }
    __syncthreads();
    int col = threadIdx.x * 4;
    f32x4 a0 = *(const f32x4*)(yrow + (size_t)(SH0 + t) * H_ + col);
    f32x4 a1 = *(const f32x4*)(yrow + (size_t)(SH1 + t) * H_ + col);
    f32x4 acc;
#pragma unroll
    for (int j = 0; j < 4; ++j) acc[j] = a0[j] + a1[j];
#pragma unroll
    for (int k = 0; k < KSEL; ++k) {
        f32x4 v = *(const f32x4*)(yrow + (size_t)sl[k] * H_ + col);
        float w = sw[k];
#pragma unroll
        for (int j = 0; j < 4; ++j) acc[j] += v[j] * w;
    }
    *(f32x4*)(out + (size_t)t * H_ + col) = acc;
}

extern "C" void kernel_launch(void* const* d_in, const int* in_sizes, int n_in,
                              void* d_out, int out_size, void* d_ws, size_t ws_size,
                              hipStream_t stream) {
    const float* x      = (const float*)d_in[0];
    const float* gate_w = (const float*)d_in[1];
    const float* w_gu   = (const float*)d_in[2];
    const float* w_d    = (const float*)d_in[3];
    const float* s_gu   = (const float*)d_in[4];
    const float* s_d    = (const float*)d_in[5];
    float* out = (float*)d_out;

    char* ws = (char*)d_ws;
    size_t off = 0;
    auto carve = [&](size_t bytes) -> void* {
        void* p = ws + off;
        off += (bytes + 255) & ~(size_t)255;
        return p;
    };
    int* counts            = (int*)carve(NJOB * 4);
    int* offsets           = (int*)carve((NJOB + 1) * 4);
    int* cursor            = (int*)carve(NJOB * 4);
    int* topk_idx          = (int*)carve(T_ * KSEL * 4);
    float* topk_w          = (float*)carve(T_ * KSEL * 4);
    int* row_token         = (int*)carve(ROWS_TOTAL * 4);
    int* slot_map          = (int*)carve(T_ * KSEL * 4);
    unsigned short* xb     = (unsigned short*)carve((size_t)T_ * H_ * 2);
    unsigned short* hidden = (unsigned short*)carve((size_t)ROWS_TOTAL * I_ * 2);
    float* yrow            = (float*)carve((size_t)ROWS_TOTAL * H_ * 4);   // 40 MB

    hipMemsetAsync(counts, 0, NJOB * 4, stream);

    cvt_x_kernel<<<(T_ * H_ / 4) / 256, 256, 0, stream>>>(x, xb);
    gate_kernel<<<T_ / 4, 256, 0, stream>>>(x, gate_w, counts, topk_idx, topk_w);
    prefix_kernel<<<1, 128, 0, stream>>>(counts, offsets, cursor);
    place_kernel<<<(ROWS_TOTAL + 255) / 256, 256, 0, stream>>>(topk_idx, offsets,
                                                               cursor, row_token, slot_map);
    gateup_kernel<<<dim3(NJOB, T_ / 256, I_ / 64), 512, 0, stream>>>(xb, w_gu, s_gu, offsets,
                                                                     row_token, hidden);
    down_kernel<<<dim3(NJOB, T_ / 256, H_ / 64), 512, 0, stream>>>(hidden, w_d, s_d, offsets,
                                                                   yrow);
    reduce_kernel<<<T_, 256, 0, stream>>>(yrow, slot_map, topk_w, out);
}